// Round 11
// baseline (277.265 us; speedup 1.0000x reference)
//
#include <hip/hip_runtime.h>

#define N_NODES 100000
#define N_EDGES 1600000
#define IN_DIM 128
#define HID_DIM 128
#define OUT_DIM 64
#define BKT_SHIFT 7
#define BKT_SIZE 128
#define NBKT ((N_NODES + BKT_SIZE - 1) / BKT_SIZE)  // 782
#define B1 256                                       // hist/scatter blocks
#define HIST_N (NBKT * B1)                           // 200192
#define HIST_N2 (2 * HIST_N)                         // 400384
#define GEMM_BLKS ((N_NODES + 127) / 128)            // 782
#define GEMM_A 391                                   // gemm blocks in scatter
#define AGG_BLKS 2048
#define NPW 13  // nodes per wave: ceil(100000 / (2048*4))

typedef float v2f __attribute__((ext_vector_type(2)));
typedef float v4f __attribute__((ext_vector_type(4)));
typedef short v8s __attribute__((ext_vector_type(8)));

// XCD-affine slot permutation: adjacent hist slots belong to same-XCD blocks.
__device__ __forceinline__ int permb(int b) { return ((b & 7) << 5) | (b >> 3); }

// ---------- helpers ----------
__device__ __forceinline__ unsigned int f2bf(float f) {  // fp32->bf16 RNE
  unsigned int u = __float_as_uint(f);
  return (u + 0x7FFFu + ((u >> 16) & 1u)) >> 16;
}

template <bool HI>
__device__ __forceinline__ v2f cvt8(unsigned int u) {
  return __builtin_amdgcn_cvt_pk_f32_fp8((int)u, HI);  // word-select immediate
}

__device__ __forceinline__ float redq(float v) {  // sum across the 4 lane-groups
  v += __shfl_xor(v, 16);
  v += __shfl_xor(v, 32);
  return v;
}

__device__ __forceinline__ void load4(const void* ei, int is64, int half, int base,
                                      int* v) {
  if (is64) {
    const long long* e = (const long long*)ei + (size_t)half * N_EDGES + base;
    longlong2 a = *(const longlong2*)e;
    longlong2 b = *(const longlong2*)(e + 2);
    v[0] = (int)a.x; v[1] = (int)a.y; v[2] = (int)b.x; v[3] = (int)b.y;
  } else {
    const int* e = (const int*)ei + (size_t)half * N_EDGES + base;
    int4 a = *(const int4*)e;
    v[0] = a.x; v[1] = a.y; v[2] = a.z; v[3] = a.w;
  }
}

// block-local int64 detection: odd dwords of first 256 int64 entries all zero
__device__ __forceinline__ int detect64_block(const unsigned int* ei, int* sh) {
  if (threadIdx.x == 0) *sh = 0;
  __syncthreads();
  if (ei[1 + 2 * threadIdx.x] != 0u) *sh = 1;
  __syncthreads();
  return (*sh == 0) ? 1 : 0;
}

// ---------- GEMM role (device fn): G_perm(fp8) = x @ W1 for rows [row0,row0+128) --
// Two-pass W^T staging (cols 0-63 then 64-127) -> 17.4KB LDS so host kernels
// keep occupancy. x goes global->reg. G stored in PERMUTED layout: logical col
// L at byte (L&15)*8+(L>>4) of the row -> one coalesced uint2 store per row-part.
// G bytes identical to R10 (same converts, same layout).
__device__ void gemm_role(const float* __restrict__ x, const float* __restrict__ W,
                          unsigned int* __restrict__ G, int row0, char* smem) {
  typedef unsigned short us_row[136];
  us_row* lwt = (us_row*)smem;  // [64][136] bf16
  const int t = threadIdx.x;
  const int lane = t & 63;
  const int wv = t >> 6;
  const int m0 = wv * 32;
  const int lrow = lane & 15;
  const int lk = (lane >> 4) * 8;

  // A fragments: direct global->reg with f2bf
  v8s a0r[4], a1r[4];
  {
    const int r0 = row0 + m0 + lrow;
    const int r1 = r0 + 16;
    const float* x0 = x + (size_t)r0 * IN_DIM + lk;
    const float* x1 = x + (size_t)r1 * IN_DIM + lk;
    const bool ok0 = r0 < N_NODES, ok1 = r1 < N_NODES;
    const float4 z4 = make_float4(0.f, 0.f, 0.f, 0.f);
#pragma unroll
    for (int kq = 0; kq < 4; ++kq) {
      float4 fa = z4, fb = z4, fc = z4, fd = z4;
      if (ok0) { fa = *(const float4*)(x0 + kq * 32); fb = *(const float4*)(x0 + kq * 32 + 4); }
      if (ok1) { fc = *(const float4*)(x1 + kq * 32); fd = *(const float4*)(x1 + kq * 32 + 4); }
      v8s p, q;
      p[0] = (short)f2bf(fa.x); p[1] = (short)f2bf(fa.y);
      p[2] = (short)f2bf(fa.z); p[3] = (short)f2bf(fa.w);
      p[4] = (short)f2bf(fb.x); p[5] = (short)f2bf(fb.y);
      p[6] = (short)f2bf(fb.z); p[7] = (short)f2bf(fb.w);
      q[0] = (short)f2bf(fc.x); q[1] = (short)f2bf(fc.y);
      q[2] = (short)f2bf(fc.z); q[3] = (short)f2bf(fc.w);
      q[4] = (short)f2bf(fd.x); q[5] = (short)f2bf(fd.y);
      q[6] = (short)f2bf(fd.z); q[7] = (short)f2bf(fd.w);
      a0r[kq] = p;
      a1r[kq] = q;
    }
  }

  v4f acc[2][8];
#pragma unroll
  for (int si = 0; si < 2; si++)
#pragma unroll
    for (int n = 0; n < 8; n++) acc[si][n] = (v4f){0.f, 0.f, 0.f, 0.f};

#pragma unroll
  for (int h = 0; h < 2; ++h) {
    if (h) __syncthreads();  // previous half's reads done
    {  // stage W^T half: cols [64h, 64h+64)
      const float4* W4 = (const float4*)W;
#pragma unroll
      for (int it = 0; it < 8; ++it) {
        const int idx = t + 256 * it;      // k*16 + c16
        const int k = idx >> 4, c4 = (idx & 15) * 4;
        float4 w = W4[k * 32 + 16 * h + (idx & 15)];
        lwt[c4 + 0][k] = (unsigned short)f2bf(w.x);
        lwt[c4 + 1][k] = (unsigned short)f2bf(w.y);
        lwt[c4 + 2][k] = (unsigned short)f2bf(w.z);
        lwt[c4 + 3][k] = (unsigned short)f2bf(w.w);
      }
    }
    __syncthreads();
#pragma unroll
    for (int kq = 0; kq < 4; ++kq) {
      const int kk = kq * 32;
      const v8s a0 = a0r[kq];
      const v8s a1 = a1r[kq];
#pragma unroll
      for (int nl = 0; nl < 4; nl++) {
        const int n = 4 * h + nl;
        v8s b = *(const v8s*)&lwt[nl * 16 + lrow][kk + lk];
        acc[0][n] = __builtin_amdgcn_mfma_f32_16x16x32_bf16(a0, b, acc[0][n], 0, 0, 0);
        acc[1][n] = __builtin_amdgcn_mfma_f32_16x16x32_bf16(a1, b, acc[1][n], 0, 0, 0);
      }
    }
  }

  // epilogue: permuted-layout pack, one uint2 store per (si,i) row
  uint2* Gv = (uint2*)G;
#pragma unroll
  for (int si = 0; si < 2; si++)
#pragma unroll
    for (int i = 0; i < 4; i++) {
      const int rr = row0 + m0 + si * 16 + (lane >> 4) * 4 + i;
      if (rr < N_NODES) {
        int w0 = __builtin_amdgcn_cvt_pk_fp8_f32(acc[si][0][i], acc[si][1][i], 0, false);
        w0 = __builtin_amdgcn_cvt_pk_fp8_f32(acc[si][2][i], acc[si][3][i], w0, true);
        int w1 = __builtin_amdgcn_cvt_pk_fp8_f32(acc[si][4][i], acc[si][5][i], 0, false);
        w1 = __builtin_amdgcn_cvt_pk_fp8_f32(acc[si][6][i], acc[si][7][i], w1, true);
        Gv[(size_t)rr * 16 + lrow] = make_uint2((unsigned)w0, (unsigned)w1);
      }
    }
}

// ---------- hist kernel: standalone (unblocks scan1 without waiting on GEMM) ----
__global__ __launch_bounds__(256) void hist_kernel(const void* ei, int* hist,
                                                   float* S) {
  __shared__ int hd[NBKT], hs[NBKT], sh[1];
  const int hb = blockIdx.x;
  const int pj = permb(hb);  // XCD-affine slot
  if (hb == 0 && threadIdx.x < HID_DIM) S[threadIdx.x] = 0.f;
  const int is64 = detect64_block((const unsigned int*)ei, sh);
  for (int k = threadIdx.x; k < NBKT; k += 256) { hd[k] = 0; hs[k] = 0; }
  __syncthreads();
  for (int g = hb * 256 + threadIdx.x; g < N_EDGES / 4; g += B1 * 256) {
    int r[4], c[4];
    load4(ei, is64, 0, g * 4, r);
    load4(ei, is64, 1, g * 4, c);
#pragma unroll
    for (int k = 0; k < 4; k++) {
      atomicAdd(&hd[c[k] >> BKT_SHIFT], 1);
      atomicAdd(&hs[r[k] >> BKT_SHIFT], 1);
    }
  }
  __syncthreads();
  for (int k = threadIdx.x; k < NBKT; k += 256) {
    hist[k * B1 + pj] = hd[k];
    hist[HIST_N + k * B1 + pj] = hs[k];
  }
}

// ---------- scan1: per-block exclusive partials + block sums ----------
__global__ void scan1_kernel(int* arr, int* bsum, int n) {
  __shared__ int tmp[256];
  int i = blockIdx.x * 256 + threadIdx.x;
  int v = (i < n) ? arr[i] : 0;
  tmp[threadIdx.x] = v;
  __syncthreads();
  for (int off = 1; off < 256; off <<= 1) {
    int t2 = (threadIdx.x >= off) ? tmp[threadIdx.x - off] : 0;
    __syncthreads();
    tmp[threadIdx.x] += t2;
    __syncthreads();
  }
  if (i < n) arr[i] = tmp[threadIdx.x] - v;  // exclusive within block
  if (threadIdx.x == 255) bsum[blockIdx.x] = tmp[255];
}

// ---------- scan2: exclusive scan of up to 2048 block sums (2/thread) ----------
__global__ void scan2_kernel(int* bsum, int nb) {
  __shared__ int tmp[1024];
  const int t = threadIdx.x;  // 1024
  int v0 = (2 * t < nb) ? bsum[2 * t] : 0;
  int v1 = (2 * t + 1 < nb) ? bsum[2 * t + 1] : 0;
  int s = v0 + v1;
  tmp[t] = s;
  __syncthreads();
  for (int off = 1; off < 1024; off <<= 1) {
    int t2 = (t >= off) ? tmp[t - off] : 0;
    __syncthreads();
    tmp[t] += t2;
    __syncthreads();
  }
  int excl = tmp[t] - s;
  if (2 * t < nb) bsum[2 * t] = excl;
  if (2 * t + 1 < nb) bsum[2 * t + 1] = excl + v0;
}

// ---------- scatter + gemm part A (role by blockIdx) ----------
// Scatter is latency/atomic-bound at 1 block/CU; co-resident GEMM blocks fill
// the idle issue slots, taking the GEMM off the serial critical path.
__global__ __launch_bounds__(256) void scatter_kernel(const void* ei, const int* hist,
                                                      const int* bsum,
                                                      unsigned int* pairs,
                                                      const float* __restrict__ x,
                                                      const float* __restrict__ W,
                                                      unsigned int* __restrict__ G) {
  __shared__ __align__(16) char smem[64 * 136 * 2];  // 17408 B (union of roles)
  if (blockIdx.x >= B1) {
    gemm_role(x, W, G, (blockIdx.x - B1) * 128, smem);
    return;
  }
  int* cd = (int*)smem;          // NBKT
  int* cs = cd + NBKT;           // NBKT
  int* sh = cs + NBKT;
  const int is64 = detect64_block((const unsigned int*)ei, sh);
  const int pj = permb(blockIdx.x);
  for (int k = threadIdx.x; k < NBKT; k += 256) {
    cd[k] = hist[k * B1 + pj] + bsum[k];
    cs[k] = hist[HIST_N + k * B1 + pj] + bsum[NBKT + k];
  }
  __syncthreads();
  for (int g = blockIdx.x * 256 + threadIdx.x; g < N_EDGES / 4; g += B1 * 256) {
    int r[4], c[4];
    load4(ei, is64, 0, g * 4, r);
    load4(ei, is64, 1, g * 4, c);
#pragma unroll
    for (int k = 0; k < 4; k++) {
      int pd = atomicAdd(&cd[c[k] >> BKT_SHIFT], 1);
      pairs[pd] = ((unsigned int)(c[k] & (BKT_SIZE - 1)) << 17) | (unsigned int)r[k];
      int ps = atomicAdd(&cs[r[k] >> BKT_SHIFT], 1);
      pairs[ps] = ((unsigned int)(r[k] & (BKT_SIZE - 1)) << 17) | (unsigned int)c[k];
    }
  }
}

// ---------- csrA: per-bucket count + scan -> rowptr + dinv (no scatter) ----------
__global__ __launch_bounds__(256) void csrA_kernel(const int* hist, const int* bsum,
                                                   const unsigned int* pairs,
                                                   int* rowptr, float* dinv) {
  __shared__ int cnt[BKT_SIZE], sc[BKT_SIZE];
  const int k = blockIdx.x;
  const int base = hist[k * B1] + bsum[k];
  const int end = (k == NBKT - 1) ? N_EDGES : hist[(k + 1) * B1] + bsum[k + 1];
  const int nseg = end - base;
  const int l = threadIdx.x;
  if (l < BKT_SIZE) cnt[l] = 0;
  __syncthreads();
  for (int i = l; i < nseg; i += 256) atomicAdd(&cnt[pairs[base + i] >> 17], 1);
  __syncthreads();
  if (l < BKT_SIZE) sc[l] = cnt[l];
  __syncthreads();
  for (int off = 1; off < BKT_SIZE; off <<= 1) {
    int v = (l < BKT_SIZE && l >= off) ? sc[l - off] : 0;
    __syncthreads();
    if (l < BKT_SIZE) sc[l] += v;
    __syncthreads();
  }
  if (l < BKT_SIZE) {
    int excl = sc[l] - cnt[l];
    int v = k * BKT_SIZE + l;
    if (v < N_NODES) {
      rowptr[v] = base + excl;
      dinv[v] = rsqrtf((float)(cnt[l] + 1));
    }
  }
  if (k == NBKT - 1 && l == 0) rowptr[N_NODES] = N_EDGES;
}

// ---------- csrB + outsum + gemm part B (role by blockIdx), x4 unrolled ----------
__global__ __launch_bounds__(256) void csrBout_kernel(const int* hist, const int* bsum,
                                                      const unsigned int* pairs,
                                                      const int* __restrict__ rowptr,
                                                      const float* __restrict__ dinv,
                                                      unsigned int* __restrict__ csr,
                                                      float* __restrict__ wacc,
                                                      const float* __restrict__ x,
                                                      const float* __restrict__ W,
                                                      unsigned int* __restrict__ G) {
  __shared__ __align__(16) char smem[64 * 136 * 2];  // 17408 B (union of roles)
  if (blockIdx.x >= 2 * NBKT) {
    gemm_role(x, W, G, (GEMM_A + blockIdx.x - 2 * NBKT) * 128, smem);
    return;
  }
  if (blockIdx.x < NBKT) {
    // ---- csrB role: scatter with bf16(dinv[src]) packed ----
    int* cur = (int*)smem;  // BKT_SIZE
    const int k = blockIdx.x;
    const int base = hist[k * B1] + bsum[k];
    const int end = (k == NBKT - 1) ? N_EDGES : hist[(k + 1) * B1] + bsum[k + 1];
    const int nseg = end - base;
    const int l = threadIdx.x;
    if (l < BKT_SIZE) {
      int v = k * BKT_SIZE + l;
      cur[l] = (v < N_NODES) ? rowptr[v] : 0;
    }
    __syncthreads();
    int i = l;
    for (; i + 768 < nseg; i += 1024) {
      const unsigned int pk0 = pairs[base + i];
      const unsigned int pk1 = pairs[base + i + 256];
      const unsigned int pk2 = pairs[base + i + 512];
      const unsigned int pk3 = pairs[base + i + 768];
      const unsigned int s0 = pk0 & 0x1FFFFu, s1 = pk1 & 0x1FFFFu;
      const unsigned int s2 = pk2 & 0x1FFFFu, s3 = pk3 & 0x1FFFFu;
      const float d0 = dinv[s0], d1 = dinv[s1], d2 = dinv[s2], d3 = dinv[s3];
      const int p0 = atomicAdd(&cur[pk0 >> 17], 1);
      const int p1 = atomicAdd(&cur[pk1 >> 17], 1);
      const int p2 = atomicAdd(&cur[pk2 >> 17], 1);
      const int p3 = atomicAdd(&cur[pk3 >> 17], 1);
      csr[p0] = (f2bf(d0) << 17) | s0;
      csr[p1] = (f2bf(d1) << 17) | s1;
      csr[p2] = (f2bf(d2) << 17) | s2;
      csr[p3] = (f2bf(d3) << 17) | s3;
    }
    for (; i < nseg; i += 256) {
      const unsigned int pk = pairs[base + i];
      const unsigned int src = pk & 0x1FFFFu;
      const int pos = atomicAdd(&cur[pk >> 17], 1);
      csr[pos] = (f2bf(dinv[src]) << 17) | src;
    }
    return;
  }
  // ---- outsum role ----
  float* fb = (float*)smem;  // BKT_SIZE
  const int k = blockIdx.x - NBKT;
  const int base = hist[HIST_N + k * B1] + bsum[NBKT + k];
  const int end =
      (k == NBKT - 1) ? 2 * N_EDGES : hist[HIST_N + (k + 1) * B1] + bsum[NBKT + k + 1];
  if (threadIdx.x < BKT_SIZE) fb[threadIdx.x] = 0.f;
  __syncthreads();
  int i = base + threadIdx.x;
  for (; i + 768 < end; i += 1024) {
    const unsigned int pk0 = pairs[i];
    const unsigned int pk1 = pairs[i + 256];
    const unsigned int pk2 = pairs[i + 512];
    const unsigned int pk3 = pairs[i + 768];
    const float d0 = dinv[pk0 & 0x1FFFFu];
    const float d1 = dinv[pk1 & 0x1FFFFu];
    const float d2 = dinv[pk2 & 0x1FFFFu];
    const float d3 = dinv[pk3 & 0x1FFFFu];
    atomicAdd(&fb[pk0 >> 17], d0);
    atomicAdd(&fb[pk1 >> 17], d1);
    atomicAdd(&fb[pk2 >> 17], d2);
    atomicAdd(&fb[pk3 >> 17], d3);
  }
  for (; i < end; i += 256) {
    const unsigned int pk = pairs[i];
    atomicAdd(&fb[pk >> 17], dinv[pk & 0x1FFFFu]);
  }
  __syncthreads();
  int v = k * BKT_SIZE + threadIdx.x;
  if (threadIdx.x < BKT_SIZE && v < N_NODES) wacc[v] = fb[threadIdx.x];
}

// ---------- aggregate (v3): 2-deep pipeline; bias/S remapped for permuted G ----
// Storage byte j of a lane's uint2 (r = lane&15) holds LOGICAL col r + 16*j.
__global__ __launch_bounds__(256) void aggregate_kernel(
    const unsigned int* __restrict__ G, const int* __restrict__ rowptr,
    const unsigned int* __restrict__ csr, const float* __restrict__ dinv,
    const float* __restrict__ wacc, const float* __restrict__ b1,
    float* __restrict__ S) {
  __shared__ float lb[HID_DIM];
  __shared__ float ls[HID_DIM];
  if (threadIdx.x < HID_DIM) {
    lb[threadIdx.x] = b1[threadIdx.x];
    ls[threadIdx.x] = 0.f;
  }
  __syncthreads();

  const int lane = threadIdx.x & 63;
  const int q = lane >> 4;   // edge-slot group 0..3
  const int r = lane & 15;   // storage segment (logical cols r+16j)
  const int wid = blockIdx.x * 4 + (threadIdx.x >> 6);
  const int c0 = wid * NPW;
  const uint2* __restrict__ G2 = (const uint2*)G;

  int rp = 0;
  float dvv = 0.f, wvv = 0.f;
  {
    const int ci = c0 + lane;
    if (lane <= NPW && ci <= N_NODES) rp = rowptr[ci];
    if (lane < NPW && ci < N_NODES) { dvv = dinv[ci]; wvv = wacc[ci]; }
  }

  v2f s01 = {0.f, 0.f}, s23 = {0.f, 0.f}, s45 = {0.f, 0.f}, s67 = {0.f, 0.f};
  const int nn = (c0 < N_NODES) ? min(NPW, N_NODES - c0) : 0;

  if (nn > 0) {
    int kF = 0, jF = 0;
    const int sF0 = __shfl(rp, 0);
    int cnumF = __shfl(rp, 1) - sF0;
    int SF = max(1, (cnumF + 15) >> 4);
    unsigned int pwW = 0;
    if (lane < cnumF) pwW = __builtin_nontemporal_load(&csr[sF0 + lane]);
    int sN = __shfl(rp, 1);
    int eN = __shfl(rp, 2);
    unsigned int pwN = 0;
    if (1 < nn && sN + lane < eN) pwN = __builtin_nontemporal_load(&csr[sN + lane]);

    int kC = 0, jC = 0;
    int SC = SF;
    float dC = __shfl(dvv, 0), waC = __shfl(wvv, 0);
    v2f a01 = {0.f, 0.f}, a23 = {0.f, 0.f}, a45 = {0.f, 0.f}, a67 = {0.f, 0.f};

    uint2 gA[4], gB[4], gSA, gSB;
    unsigned int wpA[2], wpB[2];

    auto FETCH = [&](uint2(&g)[4], unsigned int(&wp)[2], uint2& gS) {
      if (jF != 0 && (jF & 3) == 0) {  // rare: deg > 64, reload window
        const int sAbs = __shfl(rp, kF) + (jF << 4);
        pwW = 0;
        if ((jF << 4) + lane < cnumF)
          pwW = __builtin_nontemporal_load(&csr[sAbs + lane]);
      }
      const int base = (jF & 3) << 4;
      const int eg0 = (jF << 4) + q;
      unsigned int wb[4];
#pragma unroll
      for (int t = 0; t < 4; ++t) {
        const unsigned int p = __shfl(pwW, base + 4 * t + q);
        const bool vld = eg0 + 4 * t < cnumF;
        wb[t] = vld ? ((p >> 17) << 16) : 0u;
        g[t] = make_uint2(0u, 0u);
        if (vld) g[t] = G2[(size_t)(p & 0x1FFFFu) * 16 + r];
      }
      wp[0] = wb[0] | (wb[1] >> 16);
      wp[1] = wb[2] | (wb[3] >> 16);
      if (jF == 0) {  // self-loop row prefetch (q==0 lanes)
        gS = make_uint2(0u, 0u);
        if (q == 0) gS = G2[(size_t)(c0 + kF) * 16 + r];
      }
      if (jF + 1 < SF) { jF++; return; }
      kF++; jF = 0;
      if (kF < nn) {
        pwW = pwN;
        cnumF = eN - sN;
        SF = max(1, (cnumF + 15) >> 4);
        if (kF + 1 < nn) {
          sN = __shfl(rp, kF + 1);
          eN = __shfl(rp, kF + 2);
          pwN = 0;
          if (sN + lane < eN) pwN = __builtin_nontemporal_load(&csr[sN + lane]);
        }
      }
    };

    auto CONSUME = [&](const uint2(&g)[4], const unsigned int(&wp)[2],
                       const uint2& gS) -> bool {
      const float w0 = __uint_as_float(wp[0] & 0xFFFF0000u);
      const float w1 = __uint_as_float(wp[0] << 16);
      const float w2 = __uint_as_float(wp[1] & 0xFFFF0000u);
      const float w3 = __uint_as_float(wp[1] << 16);
      a01 += cvt8<false>(g[0].x) * w0; a23 += cvt8<true>(g[0].x) * w0;
      a45 += cvt8<false>(g[0].y) * w0; a67 += cvt8<true>(g[0].y) * w0;
      a01 += cvt8<false>(g[1].x) * w1; a23 += cvt8<true>(g[1].x) * w1;
      a45 += cvt8<false>(g[1].y) * w1; a67 += cvt8<true>(g[1].y) * w1;
      a01 += cvt8<false>(g[2].x) * w2; a23 += cvt8<true>(g[2].x) * w2;
      a45 += cvt8<false>(g[2].y) * w2; a67 += cvt8<true>(g[2].y) * w2;
      a01 += cvt8<false>(g[3].x) * w3; a23 += cvt8<true>(g[3].x) * w3;
      a45 += cvt8<false>(g[3].y) * w3; a67 += cvt8<true>(g[3].y) * w3;
      if (jC == 0 && q == 0) {  // self loop, weight dC
        a01 += cvt8<false>(gS.x) * dC; a23 += cvt8<true>(gS.x) * dC;
        a45 += cvt8<false>(gS.y) * dC; a67 += cvt8<true>(gS.y) * dC;
      }
      if (jC + 1 < SC) { jC++; return true; }
      // node end: reduce 4 edge-groups, relu, accumulate (permuted col map)
      const float A0 = redq(a01.x), A1 = redq(a01.y);
      const float A2 = redq(a23.x), A3 = redq(a23.y);
      const float A4 = redq(a45.x), A5 = redq(a45.y);
      const float A6 = redq(a67.x), A7 = redq(a67.y);
      if (q == 0) {
        const float wc = dC * (waC + dC);  // layer-2 weight
        s01.x += wc * fmaxf(fmaf(dC, A0, lb[r]), 0.f);
        s01.y += wc * fmaxf(fmaf(dC, A1, lb[r + 16]), 0.f);
        s23.x += wc * fmaxf(fmaf(dC, A2, lb[r + 32]), 0.f);
        s23.y += wc * fmaxf(fmaf(dC, A3, lb[r + 48]), 0.f);
        s45.x += wc * fmaxf(fmaf(dC, A4, lb[r + 64]), 0.f);
        s45.y += wc * fmaxf(fmaf(dC, A5, lb[r + 80]), 0.f);
        s67.x += wc * fmaxf(fmaf(dC, A6, lb[r + 96]), 0.f);
        s67.y += wc * fmaxf(fmaf(dC, A7, lb[r + 112]), 0.f);
      }
      a01 = (v2f){0.f, 0.f}; a23 = (v2f){0.f, 0.f};
      a45 = (v2f){0.f, 0.f}; a67 = (v2f){0.f, 0.f};
      kC++; jC = 0;
      if (kC >= nn) return false;
      const int s_ = __shfl(rp, kC);
      const int cnumC = __shfl(rp, kC + 1) - s_;
      SC = max(1, (cnumC + 15) >> 4);
      dC = __shfl(dvv, kC);
      waC = __shfl(wvv, kC);
      return true;
    };

    FETCH(gA, wpA, gSA);
    for (;;) {
      if (kF < nn) FETCH(gB, wpB, gSB);
      if (!CONSUME(gA, wpA, gSA)) break;
      if (kF < nn) FETCH(gA, wpA, gSA);
      if (!CONSUME(gB, wpB, gSB)) break;
    }
  }

  if (q == 0) {
    atomicAdd(&ls[r], s01.x);       atomicAdd(&ls[r + 16], s01.y);
    atomicAdd(&ls[r + 32], s23.x);  atomicAdd(&ls[r + 48], s23.y);
    atomicAdd(&ls[r + 64], s45.x);  atomicAdd(&ls[r + 80], s45.y);
    atomicAdd(&ls[r + 96], s67.x);  atomicAdd(&ls[r + 112], s67.y);
  }
  __syncthreads();
  if (threadIdx.x < HID_DIM) atomicAdd(&S[threadIdx.x], ls[threadIdx.x]);
}

// ---------- out[j] = (1/N) * S @ W2 + b2 ----------
__global__ void finish_kernel(const float* __restrict__ S, const float* __restrict__ W2,
                              const float* __restrict__ b2, float* __restrict__ out) {
  int j = threadIdx.x;  // 64
  float acc = 0.f;
  for (int k = 0; k < HID_DIM; k++) acc += S[k] * W2[k * OUT_DIM + j];
  out[j] = acc * (1.0f / N_NODES) + b2[j];
}

extern "C" void kernel_launch(void* const* d_in, const int* in_sizes, int n_in,
                              void* d_out, int out_size, void* d_ws, size_t ws_size,
                              hipStream_t stream) {
  const float* x  = (const float*)d_in[0];
  const void*  ei = d_in[1];
  const float* W1 = (const float*)d_in[2];
  const float* b1 = (const float*)d_in[3];
  const float* W2 = (const float*)d_in[4];
  const float* b2 = (const float*)d_in[5];
  float* out = (float*)d_out;

  char* p = (char*)d_ws;
  size_t off = 0;
  auto alloc = [&](size_t bytes) -> void* {
    void* r = p + off;
    off = (off + bytes + 63) & ~(size_t)63;
    return r;
  };
  int*   hist   = (int*)alloc((size_t)HIST_N2 * 4);                // 1.6 MB
  int*   bsum   = (int*)alloc(2048 * 4);
  unsigned int* pairs = (unsigned int*)alloc((size_t)2 * N_EDGES * 4);  // 12.8 MB
  int*   rowptr = (int*)alloc(((size_t)N_NODES + 1) * 4);
  unsigned int* csr = (unsigned int*)alloc((size_t)N_EDGES * 4);   // 6.4 MB
  float* dinv   = (float*)alloc((size_t)N_NODES * 4);
  float* wacc   = (float*)alloc((size_t)N_NODES * 4);
  float* S      = (float*)alloc(HID_DIM * 4);
  unsigned int* G = (unsigned int*)alloc((size_t)N_NODES * HID_DIM);  // 12.8 MB fp8
  (void)ws_size; (void)n_in; (void)in_sizes; (void)out_size;

  const int NBH = HIST_N2 / 256;  // 1564, exact

  hist_kernel<<<B1, 256, 0, stream>>>(ei, hist, S);
  scan1_kernel<<<NBH, 256, 0, stream>>>(hist, bsum, HIST_N2);
  scan2_kernel<<<1, 1024, 0, stream>>>(bsum, NBH);
  scatter_kernel<<<B1 + GEMM_A, 256, 0, stream>>>(ei, hist, bsum, pairs, x, W1, G);
  csrA_kernel<<<NBKT, 256, 0, stream>>>(hist, bsum, pairs, rowptr, dinv);
  csrBout_kernel<<<2 * NBKT + (GEMM_BLKS - GEMM_A), 256, 0, stream>>>(
      hist, bsum, pairs, rowptr, dinv, csr, wacc, x, W1, G);
  aggregate_kernel<<<AGG_BLKS, 256, 0, stream>>>(G, rowptr, csr, dinv, wacc, b1, S);
  finish_kernel<<<1, 64, 0, stream>>>(S, W2, b2, out);
}

// Round 12
// 257.463 us; speedup vs baseline: 1.0769x; 1.0769x over previous
//
#include <hip/hip_runtime.h>

#define N_NODES 100000
#define N_EDGES 1600000
#define IN_DIM 128
#define HID_DIM 128
#define OUT_DIM 64
#define BKT_SHIFT 7
#define BKT_SIZE 128
#define NBKT ((N_NODES + BKT_SIZE - 1) / BKT_SIZE)  // 782
#define B1 256                                       // hist/scatter blocks
#define HIST_N (NBKT * B1)                           // 200192
#define HIST_N2 (2 * HIST_N)                         // 400384
#define GEMM_BLKS ((N_NODES + 127) / 128)            // 782
#define AGG_BLKS 2048
#define NPW 13  // nodes per wave: ceil(100000 / (2048*4))

typedef float v2f __attribute__((ext_vector_type(2)));
typedef float v4f __attribute__((ext_vector_type(4)));
typedef short v8s __attribute__((ext_vector_type(8)));

// XCD-affine slot permutation: adjacent hist slots belong to same-XCD blocks.
__device__ __forceinline__ int permb(int b) { return ((b & 7) << 5) | (b >> 3); }

// ---------- helpers ----------
__device__ __forceinline__ unsigned int f2bf(float f) {  // fp32->bf16 RNE
  unsigned int u = __float_as_uint(f);
  return (u + 0x7FFFu + ((u >> 16) & 1u)) >> 16;
}

template <bool HI>
__device__ __forceinline__ v2f cvt8(unsigned int u) {
  return __builtin_amdgcn_cvt_pk_f32_fp8((int)u, HI);  // word-select immediate
}

__device__ __forceinline__ float redq(float v) {  // sum across the 4 lane-groups
  v += __shfl_xor(v, 16);
  v += __shfl_xor(v, 32);
  return v;
}

__device__ __forceinline__ void load4(const void* ei, int is64, int half, int base,
                                      int* v) {
  if (is64) {
    const long long* e = (const long long*)ei + (size_t)half * N_EDGES + base;
    longlong2 a = *(const longlong2*)e;
    longlong2 b = *(const longlong2*)(e + 2);
    v[0] = (int)a.x; v[1] = (int)a.y; v[2] = (int)b.x; v[3] = (int)b.y;
  } else {
    const int* e = (const int*)ei + (size_t)half * N_EDGES + base;
    int4 a = *(const int4*)e;
    v[0] = a.x; v[1] = a.y; v[2] = a.z; v[3] = a.w;
  }
}

// block-local int64 detection: odd dwords of first 256 int64 entries all zero
__device__ __forceinline__ int detect64_block(const unsigned int* ei, int* sh) {
  if (threadIdx.x == 0) *sh = 0;
  __syncthreads();
  if (ei[1 + 2 * threadIdx.x] != 0u) *sh = 1;
  __syncthreads();
  return (*sh == 0) ? 1 : 0;
}

// ---------- front kernel: blocks [0,782) = raw GEMM; [782,1038) = hist ----------
// GEMM role: x loaded global->reg (no x LDS; each row consumed by one wave only)
// -> LDS 69.6KB -> 34.8KB -> 4 blocks/CU. G stored fp8 in PERMUTED layout:
// logical col L lives at byte (L&15)*8 + (L>>4) of the row, so each lane's 8
// outputs per row form ONE uint2 store (lanes 0-15 = one full 128B row,
// perfectly coalesced; kills the 64MB write-allocate seen in R9 counters).
__global__ __launch_bounds__(256) void front_kernel(const float* __restrict__ x,
                                                    const float* __restrict__ W,
                                                    const void* ei,
                                                    unsigned int* __restrict__ G,
                                                    int* hist, float* S) {
  __shared__ __align__(16) char smem[128 * 136 * 2];  // 34816 B (W^T only)
  if (blockIdx.x >= GEMM_BLKS) {
    // ---- hist role ----
    int* hd = (int*)smem;           // NBKT
    int* hs = hd + NBKT;            // NBKT
    int* sh = hs + NBKT;
    const int hb = blockIdx.x - GEMM_BLKS;
    const int pj = permb(hb);       // XCD-affine slot
    if (hb == 0 && threadIdx.x < HID_DIM) S[threadIdx.x] = 0.f;
    const int is64 = detect64_block((const unsigned int*)ei, sh);
    for (int k = threadIdx.x; k < NBKT; k += 256) { hd[k] = 0; hs[k] = 0; }
    __syncthreads();
    for (int g = hb * 256 + threadIdx.x; g < N_EDGES / 4; g += B1 * 256) {
      int r[4], c[4];
      load4(ei, is64, 0, g * 4, r);
      load4(ei, is64, 1, g * 4, c);
#pragma unroll
      for (int k = 0; k < 4; k++) {
        atomicAdd(&hd[c[k] >> BKT_SHIFT], 1);
        atomicAdd(&hs[r[k] >> BKT_SHIFT], 1);
      }
    }
    __syncthreads();
    for (int k = threadIdx.x; k < NBKT; k += 256) {
      hist[k * B1 + pj] = hd[k];
      hist[HIST_N + k * B1 + pj] = hs[k];
    }
    return;
  }
  // ---- gemm role: G_perm(fp8) = x @ W1, bf16 MFMA ----
  typedef unsigned short us_row[136];
  us_row* lwt = (us_row*)smem;
  const int t = threadIdx.x;
  const int row0 = blockIdx.x * 128;

  const int lane = t & 63;
  const int wv = t >> 6;
  const int m0 = wv * 32;
  const int lrow = lane & 15;
  const int lk = (lane >> 4) * 8;

  // A fragments: direct global->reg with f2bf (x is L3-resident across iters;
  // issue all 16 loads before the W barrier so they fill in flight).
  v8s a0r[4], a1r[4];
  {
    const int r0 = row0 + m0 + lrow;
    const int r1 = r0 + 16;
    const float* x0 = x + (size_t)r0 * IN_DIM + lk;
    const float* x1 = x + (size_t)r1 * IN_DIM + lk;
    const bool ok0 = r0 < N_NODES, ok1 = r1 < N_NODES;
    const float4 z4 = make_float4(0.f, 0.f, 0.f, 0.f);
#pragma unroll
    for (int kq = 0; kq < 4; ++kq) {
      float4 fa = z4, fb = z4, fc = z4, fd = z4;
      if (ok0) { fa = *(const float4*)(x0 + kq * 32); fb = *(const float4*)(x0 + kq * 32 + 4); }
      if (ok1) { fc = *(const float4*)(x1 + kq * 32); fd = *(const float4*)(x1 + kq * 32 + 4); }
      v8s p, q;
      p[0] = (short)f2bf(fa.x); p[1] = (short)f2bf(fa.y);
      p[2] = (short)f2bf(fa.z); p[3] = (short)f2bf(fa.w);
      p[4] = (short)f2bf(fb.x); p[5] = (short)f2bf(fb.y);
      p[6] = (short)f2bf(fb.z); p[7] = (short)f2bf(fb.w);
      q[0] = (short)f2bf(fc.x); q[1] = (short)f2bf(fc.y);
      q[2] = (short)f2bf(fc.z); q[3] = (short)f2bf(fc.w);
      q[4] = (short)f2bf(fd.x); q[5] = (short)f2bf(fd.y);
      q[6] = (short)f2bf(fd.z); q[7] = (short)f2bf(fd.w);
      a0r[kq] = p;
      a1r[kq] = q;
    }
  }

  {  // stage W^T bf16
    const float4* W4 = (const float4*)W;
    for (int it = 0; it < 16; ++it) {
      int idx = t + 256 * it;  // k*32 + c4
      int k = idx >> 5, c4 = (idx & 31) * 4;
      float4 w = W4[idx];
      lwt[c4 + 0][k] = (unsigned short)f2bf(w.x);
      lwt[c4 + 1][k] = (unsigned short)f2bf(w.y);
      lwt[c4 + 2][k] = (unsigned short)f2bf(w.z);
      lwt[c4 + 3][k] = (unsigned short)f2bf(w.w);
    }
  }
  __syncthreads();

  v4f acc[2][8];
#pragma unroll
  for (int si = 0; si < 2; si++)
#pragma unroll
    for (int n = 0; n < 8; n++) acc[si][n] = (v4f){0.f, 0.f, 0.f, 0.f};

#pragma unroll
  for (int kq = 0; kq < 4; ++kq) {
    const int kk = kq * 32;
    const v8s a0 = a0r[kq];
    const v8s a1 = a1r[kq];
#pragma unroll
    for (int n = 0; n < 8; n++) {
      v8s b = *(const v8s*)&lwt[n * 16 + lrow][kk + lk];
      acc[0][n] = __builtin_amdgcn_mfma_f32_16x16x32_bf16(a0, b, acc[0][n], 0, 0, 0);
      acc[1][n] = __builtin_amdgcn_mfma_f32_16x16x32_bf16(a1, b, acc[1][n], 0, 0, 0);
    }
  }

  // epilogue: permuted-layout pack, one uint2 store per (si,i) row
  uint2* Gv = (uint2*)G;
#pragma unroll
  for (int si = 0; si < 2; si++)
#pragma unroll
    for (int i = 0; i < 4; i++) {
      const int rr = row0 + m0 + si * 16 + (lane >> 4) * 4 + i;
      if (rr < N_NODES) {
        int w0 = __builtin_amdgcn_cvt_pk_fp8_f32(acc[si][0][i], acc[si][1][i], 0, false);
        w0 = __builtin_amdgcn_cvt_pk_fp8_f32(acc[si][2][i], acc[si][3][i], w0, true);
        int w1 = __builtin_amdgcn_cvt_pk_fp8_f32(acc[si][4][i], acc[si][5][i], 0, false);
        w1 = __builtin_amdgcn_cvt_pk_fp8_f32(acc[si][6][i], acc[si][7][i], w1, true);
        Gv[(size_t)rr * 16 + lrow] = make_uint2((unsigned)w0, (unsigned)w1);
      }
    }
}

// ---------- scan1: per-block exclusive partials + block sums ----------
__global__ void scan1_kernel(int* arr, int* bsum, int n) {
  __shared__ int tmp[256];
  int i = blockIdx.x * 256 + threadIdx.x;
  int v = (i < n) ? arr[i] : 0;
  tmp[threadIdx.x] = v;
  __syncthreads();
  for (int off = 1; off < 256; off <<= 1) {
    int t2 = (threadIdx.x >= off) ? tmp[threadIdx.x - off] : 0;
    __syncthreads();
    tmp[threadIdx.x] += t2;
    __syncthreads();
  }
  if (i < n) arr[i] = tmp[threadIdx.x] - v;  // exclusive within block
  if (threadIdx.x == 255) bsum[blockIdx.x] = tmp[255];
}

// ---------- scan2: exclusive scan of up to 2048 block sums (2/thread) ----------
__global__ void scan2_kernel(int* bsum, int nb) {
  __shared__ int tmp[1024];
  const int t = threadIdx.x;  // 1024
  int v0 = (2 * t < nb) ? bsum[2 * t] : 0;
  int v1 = (2 * t + 1 < nb) ? bsum[2 * t + 1] : 0;
  int s = v0 + v1;
  tmp[t] = s;
  __syncthreads();
  for (int off = 1; off < 1024; off <<= 1) {
    int t2 = (t >= off) ? tmp[t - off] : 0;
    __syncthreads();
    tmp[t] += t2;
    __syncthreads();
  }
  int excl = tmp[t] - s;
  if (2 * t < nb) bsum[2 * t] = excl;
  if (2 * t + 1 < nb) bsum[2 * t + 1] = excl + v0;
}

// ---------- scatter: pairs into bucket partitions; XCD-affine slots ----------
__global__ __launch_bounds__(256) void scatter_kernel(const void* ei, const int* hist,
                                                      const int* bsum,
                                                      unsigned int* pairs) {
  __shared__ int cd[NBKT], cs[NBKT], sh[1];
  const int is64 = detect64_block((const unsigned int*)ei, sh);
  const int pj = permb(blockIdx.x);
  for (int k = threadIdx.x; k < NBKT; k += 256) {
    cd[k] = hist[k * B1 + pj] + bsum[k];
    cs[k] = hist[HIST_N + k * B1 + pj] + bsum[NBKT + k];
  }
  __syncthreads();
  for (int g = blockIdx.x * 256 + threadIdx.x; g < N_EDGES / 4; g += B1 * 256) {
    int r[4], c[4];
    load4(ei, is64, 0, g * 4, r);
    load4(ei, is64, 1, g * 4, c);
#pragma unroll
    for (int k = 0; k < 4; k++) {
      int pd = atomicAdd(&cd[c[k] >> BKT_SHIFT], 1);
      pairs[pd] = ((unsigned int)(c[k] & (BKT_SIZE - 1)) << 17) | (unsigned int)r[k];
      int ps = atomicAdd(&cs[r[k] >> BKT_SHIFT], 1);
      pairs[ps] = ((unsigned int)(r[k] & (BKT_SIZE - 1)) << 17) | (unsigned int)c[k];
    }
  }
}

// ---------- csrA: per-bucket count + scan -> rowptr + dinv (no scatter) ----------
__global__ __launch_bounds__(256) void csrA_kernel(const int* hist, const int* bsum,
                                                   const unsigned int* pairs,
                                                   int* rowptr, float* dinv) {
  __shared__ int cnt[BKT_SIZE], sc[BKT_SIZE];
  const int k = blockIdx.x;
  const int base = hist[k * B1] + bsum[k];
  const int end = (k == NBKT - 1) ? N_EDGES : hist[(k + 1) * B1] + bsum[k + 1];
  const int nseg = end - base;
  const int l = threadIdx.x;
  if (l < BKT_SIZE) cnt[l] = 0;
  __syncthreads();
  for (int i = l; i < nseg; i += 256) atomicAdd(&cnt[pairs[base + i] >> 17], 1);
  __syncthreads();
  if (l < BKT_SIZE) sc[l] = cnt[l];
  __syncthreads();
  for (int off = 1; off < BKT_SIZE; off <<= 1) {
    int v = (l < BKT_SIZE && l >= off) ? sc[l - off] : 0;
    __syncthreads();
    if (l < BKT_SIZE) sc[l] += v;
    __syncthreads();
  }
  if (l < BKT_SIZE) {
    int excl = sc[l] - cnt[l];
    int v = k * BKT_SIZE + l;
    if (v < N_NODES) {
      rowptr[v] = base + excl;
      dinv[v] = rsqrtf((float)(cnt[l] + 1));
    }
  }
  if (k == NBKT - 1 && l == 0) rowptr[N_NODES] = N_EDGES;
}

// ---------- csrB + outsum fused (role by blockIdx), x4 unrolled ----------
__global__ __launch_bounds__(256) void csrBout_kernel(const int* hist, const int* bsum,
                                                      const unsigned int* pairs,
                                                      const int* __restrict__ rowptr,
                                                      const float* __restrict__ dinv,
                                                      unsigned int* __restrict__ csr,
                                                      float* __restrict__ wacc) {
  if (blockIdx.x < NBKT) {
    // ---- csrB role: scatter with bf16(dinv[src]) packed ----
    __shared__ int cur[BKT_SIZE];
    const int k = blockIdx.x;
    const int base = hist[k * B1] + bsum[k];
    const int end = (k == NBKT - 1) ? N_EDGES : hist[(k + 1) * B1] + bsum[k + 1];
    const int nseg = end - base;
    const int l = threadIdx.x;
    if (l < BKT_SIZE) {
      int v = k * BKT_SIZE + l;
      cur[l] = (v < N_NODES) ? rowptr[v] : 0;
    }
    __syncthreads();
    int i = l;
    for (; i + 768 < nseg; i += 1024) {
      const unsigned int pk0 = pairs[base + i];
      const unsigned int pk1 = pairs[base + i + 256];
      const unsigned int pk2 = pairs[base + i + 512];
      const unsigned int pk3 = pairs[base + i + 768];
      const unsigned int s0 = pk0 & 0x1FFFFu, s1 = pk1 & 0x1FFFFu;
      const unsigned int s2 = pk2 & 0x1FFFFu, s3 = pk3 & 0x1FFFFu;
      const float d0 = dinv[s0], d1 = dinv[s1], d2 = dinv[s2], d3 = dinv[s3];
      const int p0 = atomicAdd(&cur[pk0 >> 17], 1);
      const int p1 = atomicAdd(&cur[pk1 >> 17], 1);
      const int p2 = atomicAdd(&cur[pk2 >> 17], 1);
      const int p3 = atomicAdd(&cur[pk3 >> 17], 1);
      csr[p0] = (f2bf(d0) << 17) | s0;
      csr[p1] = (f2bf(d1) << 17) | s1;
      csr[p2] = (f2bf(d2) << 17) | s2;
      csr[p3] = (f2bf(d3) << 17) | s3;
    }
    for (; i < nseg; i += 256) {
      const unsigned int pk = pairs[base + i];
      const unsigned int src = pk & 0x1FFFFu;
      const int pos = atomicAdd(&cur[pk >> 17], 1);
      csr[pos] = (f2bf(dinv[src]) << 17) | src;
    }
    return;
  }
  // ---- outsum role ----
  __shared__ float fb[BKT_SIZE];
  const int k = blockIdx.x - NBKT;
  const int base = hist[HIST_N + k * B1] + bsum[NBKT + k];
  const int end =
      (k == NBKT - 1) ? 2 * N_EDGES : hist[HIST_N + (k + 1) * B1] + bsum[NBKT + k + 1];
  if (threadIdx.x < BKT_SIZE) fb[threadIdx.x] = 0.f;
  __syncthreads();
  int i = base + threadIdx.x;
  for (; i + 768 < end; i += 1024) {
    const unsigned int pk0 = pairs[i];
    const unsigned int pk1 = pairs[i + 256];
    const unsigned int pk2 = pairs[i + 512];
    const unsigned int pk3 = pairs[i + 768];
    const float d0 = dinv[pk0 & 0x1FFFFu];
    const float d1 = dinv[pk1 & 0x1FFFFu];
    const float d2 = dinv[pk2 & 0x1FFFFu];
    const float d3 = dinv[pk3 & 0x1FFFFu];
    atomicAdd(&fb[pk0 >> 17], d0);
    atomicAdd(&fb[pk1 >> 17], d1);
    atomicAdd(&fb[pk2 >> 17], d2);
    atomicAdd(&fb[pk3 >> 17], d3);
  }
  for (; i < end; i += 256) {
    const unsigned int pk = pairs[i];
    atomicAdd(&fb[pk >> 17], dinv[pk & 0x1FFFFu]);
  }
  __syncthreads();
  int v = k * BKT_SIZE + threadIdx.x;
  if (threadIdx.x < BKT_SIZE && v < N_NODES) wacc[v] = fb[threadIdx.x];
}

// ---------- aggregate (v3): 2-deep pipeline; bias/S remapped for permuted G ----
// Storage byte j of a lane's uint2 (r = lane&15) holds LOGICAL col r + 16*j.
__global__ __launch_bounds__(256) void aggregate_kernel(
    const unsigned int* __restrict__ G, const int* __restrict__ rowptr,
    const unsigned int* __restrict__ csr, const float* __restrict__ dinv,
    const float* __restrict__ wacc, const float* __restrict__ b1,
    float* __restrict__ S) {
  __shared__ float lb[HID_DIM];
  __shared__ float ls[HID_DIM];
  if (threadIdx.x < HID_DIM) {
    lb[threadIdx.x] = b1[threadIdx.x];
    ls[threadIdx.x] = 0.f;
  }
  __syncthreads();

  const int lane = threadIdx.x & 63;
  const int q = lane >> 4;   // edge-slot group 0..3
  const int r = lane & 15;   // storage segment (logical cols r+16j)
  const int wid = blockIdx.x * 4 + (threadIdx.x >> 6);
  const int c0 = wid * NPW;
  const uint2* __restrict__ G2 = (const uint2*)G;

  int rp = 0;
  float dvv = 0.f, wvv = 0.f;
  {
    const int ci = c0 + lane;
    if (lane <= NPW && ci <= N_NODES) rp = rowptr[ci];
    if (lane < NPW && ci < N_NODES) { dvv = dinv[ci]; wvv = wacc[ci]; }
  }

  v2f s01 = {0.f, 0.f}, s23 = {0.f, 0.f}, s45 = {0.f, 0.f}, s67 = {0.f, 0.f};
  const int nn = (c0 < N_NODES) ? min(NPW, N_NODES - c0) : 0;

  if (nn > 0) {
    int kF = 0, jF = 0;
    const int sF0 = __shfl(rp, 0);
    int cnumF = __shfl(rp, 1) - sF0;
    int SF = max(1, (cnumF + 15) >> 4);
    unsigned int pwW = 0;
    if (lane < cnumF) pwW = __builtin_nontemporal_load(&csr[sF0 + lane]);
    int sN = __shfl(rp, 1);
    int eN = __shfl(rp, 2);
    unsigned int pwN = 0;
    if (1 < nn && sN + lane < eN) pwN = __builtin_nontemporal_load(&csr[sN + lane]);

    int kC = 0, jC = 0;
    int SC = SF;
    float dC = __shfl(dvv, 0), waC = __shfl(wvv, 0);
    v2f a01 = {0.f, 0.f}, a23 = {0.f, 0.f}, a45 = {0.f, 0.f}, a67 = {0.f, 0.f};

    uint2 gA[4], gB[4], gSA, gSB;
    unsigned int wpA[2], wpB[2];

    auto FETCH = [&](uint2(&g)[4], unsigned int(&wp)[2], uint2& gS) {
      if (jF != 0 && (jF & 3) == 0) {  // rare: deg > 64, reload window
        const int sAbs = __shfl(rp, kF) + (jF << 4);
        pwW = 0;
        if ((jF << 4) + lane < cnumF)
          pwW = __builtin_nontemporal_load(&csr[sAbs + lane]);
      }
      const int base = (jF & 3) << 4;
      const int eg0 = (jF << 4) + q;
      unsigned int wb[4];
#pragma unroll
      for (int t = 0; t < 4; ++t) {
        const unsigned int p = __shfl(pwW, base + 4 * t + q);
        const bool vld = eg0 + 4 * t < cnumF;
        wb[t] = vld ? ((p >> 17) << 16) : 0u;
        g[t] = make_uint2(0u, 0u);
        if (vld) g[t] = G2[(size_t)(p & 0x1FFFFu) * 16 + r];
      }
      wp[0] = wb[0] | (wb[1] >> 16);
      wp[1] = wb[2] | (wb[3] >> 16);
      if (jF == 0) {  // self-loop row prefetch (q==0 lanes)
        gS = make_uint2(0u, 0u);
        if (q == 0) gS = G2[(size_t)(c0 + kF) * 16 + r];
      }
      if (jF + 1 < SF) { jF++; return; }
      kF++; jF = 0;
      if (kF < nn) {
        pwW = pwN;
        cnumF = eN - sN;
        SF = max(1, (cnumF + 15) >> 4);
        if (kF + 1 < nn) {
          sN = __shfl(rp, kF + 1);
          eN = __shfl(rp, kF + 2);
          pwN = 0;
          if (sN + lane < eN) pwN = __builtin_nontemporal_load(&csr[sN + lane]);
        }
      }
    };

    auto CONSUME = [&](const uint2(&g)[4], const unsigned int(&wp)[2],
                       const uint2& gS) -> bool {
      const float w0 = __uint_as_float(wp[0] & 0xFFFF0000u);
      const float w1 = __uint_as_float(wp[0] << 16);
      const float w2 = __uint_as_float(wp[1] & 0xFFFF0000u);
      const float w3 = __uint_as_float(wp[1] << 16);
      a01 += cvt8<false>(g[0].x) * w0; a23 += cvt8<true>(g[0].x) * w0;
      a45 += cvt8<false>(g[0].y) * w0; a67 += cvt8<true>(g[0].y) * w0;
      a01 += cvt8<false>(g[1].x) * w1; a23 += cvt8<true>(g[1].x) * w1;
      a45 += cvt8<false>(g[1].y) * w1; a67 += cvt8<true>(g[1].y) * w1;
      a01 += cvt8<false>(g[2].x) * w2; a23 += cvt8<true>(g[2].x) * w2;
      a45 += cvt8<false>(g[2].y) * w2; a67 += cvt8<true>(g[2].y) * w2;
      a01 += cvt8<false>(g[3].x) * w3; a23 += cvt8<true>(g[3].x) * w3;
      a45 += cvt8<false>(g[3].y) * w3; a67 += cvt8<true>(g[3].y) * w3;
      if (jC == 0 && q == 0) {  // self loop, weight dC
        a01 += cvt8<false>(gS.x) * dC; a23 += cvt8<true>(gS.x) * dC;
        a45 += cvt8<false>(gS.y) * dC; a67 += cvt8<true>(gS.y) * dC;
      }
      if (jC + 1 < SC) { jC++; return true; }
      // node end: reduce 4 edge-groups, relu, accumulate (permuted col map)
      const float A0 = redq(a01.x), A1 = redq(a01.y);
      const float A2 = redq(a23.x), A3 = redq(a23.y);
      const float A4 = redq(a45.x), A5 = redq(a45.y);
      const float A6 = redq(a67.x), A7 = redq(a67.y);
      if (q == 0) {
        const float wc = dC * (waC + dC);  // layer-2 weight
        s01.x += wc * fmaxf(fmaf(dC, A0, lb[r]), 0.f);
        s01.y += wc * fmaxf(fmaf(dC, A1, lb[r + 16]), 0.f);
        s23.x += wc * fmaxf(fmaf(dC, A2, lb[r + 32]), 0.f);
        s23.y += wc * fmaxf(fmaf(dC, A3, lb[r + 48]), 0.f);
        s45.x += wc * fmaxf(fmaf(dC, A4, lb[r + 64]), 0.f);
        s45.y += wc * fmaxf(fmaf(dC, A5, lb[r + 80]), 0.f);
        s67.x += wc * fmaxf(fmaf(dC, A6, lb[r + 96]), 0.f);
        s67.y += wc * fmaxf(fmaf(dC, A7, lb[r + 112]), 0.f);
      }
      a01 = (v2f){0.f, 0.f}; a23 = (v2f){0.f, 0.f};
      a45 = (v2f){0.f, 0.f}; a67 = (v2f){0.f, 0.f};
      kC++; jC = 0;
      if (kC >= nn) return false;
      const int s_ = __shfl(rp, kC);
      const int cnumC = __shfl(rp, kC + 1) - s_;
      SC = max(1, (cnumC + 15) >> 4);
      dC = __shfl(dvv, kC);
      waC = __shfl(wvv, kC);
      return true;
    };

    FETCH(gA, wpA, gSA);
    for (;;) {
      if (kF < nn) FETCH(gB, wpB, gSB);
      if (!CONSUME(gA, wpA, gSA)) break;
      if (kF < nn) FETCH(gA, wpA, gSA);
      if (!CONSUME(gB, wpB, gSB)) break;
    }
  }

  if (q == 0) {
    atomicAdd(&ls[r], s01.x);       atomicAdd(&ls[r + 16], s01.y);
    atomicAdd(&ls[r + 32], s23.x);  atomicAdd(&ls[r + 48], s23.y);
    atomicAdd(&ls[r + 64], s45.x);  atomicAdd(&ls[r + 80], s45.y);
    atomicAdd(&ls[r + 96], s67.x);  atomicAdd(&ls[r + 112], s67.y);
  }
  __syncthreads();
  if (threadIdx.x < HID_DIM) atomicAdd(&S[threadIdx.x], ls[threadIdx.x]);
}

// ---------- out[j] = (1/N) * S @ W2 + b2 ----------
__global__ void finish_kernel(const float* __restrict__ S, const float* __restrict__ W2,
                              const float* __restrict__ b2, float* __restrict__ out) {
  int j = threadIdx.x;  // 64
  float acc = 0.f;
  for (int k = 0; k < HID_DIM; k++) acc += S[k] * W2[k * OUT_DIM + j];
  out[j] = acc * (1.0f / N_NODES) + b2[j];
}

extern "C" void kernel_launch(void* const* d_in, const int* in_sizes, int n_in,
                              void* d_out, int out_size, void* d_ws, size_t ws_size,
                              hipStream_t stream) {
  const float* x  = (const float*)d_in[0];
  const void*  ei = d_in[1];
  const float* W1 = (const float*)d_in[2];
  const float* b1 = (const float*)d_in[3];
  const float* W2 = (const float*)d_in[4];
  const float* b2 = (const float*)d_in[5];
  float* out = (float*)d_out;

  char* p = (char*)d_ws;
  size_t off = 0;
  auto alloc = [&](size_t bytes) -> void* {
    void* r = p + off;
    off = (off + bytes + 63) & ~(size_t)63;
    return r;
  };
  int*   hist   = (int*)alloc((size_t)HIST_N2 * 4);                // 1.6 MB
  int*   bsum   = (int*)alloc(2048 * 4);
  unsigned int* pairs = (unsigned int*)alloc((size_t)2 * N_EDGES * 4);  // 12.8 MB
  int*   rowptr = (int*)alloc(((size_t)N_NODES + 1) * 4);
  unsigned int* csr = (unsigned int*)alloc((size_t)N_EDGES * 4);   // 6.4 MB
  float* dinv   = (float*)alloc((size_t)N_NODES * 4);
  float* wacc   = (float*)alloc((size_t)N_NODES * 4);
  float* S      = (float*)alloc(HID_DIM * 4);
  unsigned int* G = (unsigned int*)alloc((size_t)N_NODES * HID_DIM);  // 12.8 MB fp8
  (void)ws_size; (void)n_in; (void)in_sizes; (void)out_size;

  const int NBH = HIST_N2 / 256;  // 1564, exact

  front_kernel<<<GEMM_BLKS + B1, 256, 0, stream>>>(x, W1, ei, G, hist, S);
  scan1_kernel<<<NBH, 256, 0, stream>>>(hist, bsum, HIST_N2);
  scan2_kernel<<<1, 1024, 0, stream>>>(bsum, NBH);
  scatter_kernel<<<B1, 256, 0, stream>>>(ei, hist, bsum, pairs);
  csrA_kernel<<<NBKT, 256, 0, stream>>>(hist, bsum, pairs, rowptr, dinv);
  csrBout_kernel<<<2 * NBKT, 256, 0, stream>>>(hist, bsum, pairs, rowptr, dinv, csr,
                                               wacc);
  aggregate_kernel<<<AGG_BLKS, 256, 0, stream>>>(G, rowptr, csr, dinv, wacc, b1, S);
  finish_kernel<<<1, 64, 0, stream>>>(S, W2, b2, out);
}